// Round 1
// baseline (3301.645 us; speedup 1.0000x reference)
//
#include <hip/hip_runtime.h>
#include <stdint.h>

#define NREL 65536
#define NOBJ 8192
#define NOC 151
#define NRC 51

typedef unsigned short u16;
typedef __attribute__((ext_vector_type(8))) short short8;
typedef __attribute__((ext_vector_type(4))) float f32x4;

__device__ __forceinline__ u16 f2bf(float f) {
  union { float f; uint32_t u; } v; v.f = f;
  uint32_t r = v.u + 0x7fffu + ((v.u >> 16) & 1u);
  return (u16)(r >> 16);
}

// global -> LDS direct copy, 16B per lane. lds base MUST be wave-uniform;
// lane l's data lands at base + l*16 (m104 semantics). Source may be per-lane.
__device__ __forceinline__ void gload16(const u16* g, u16* lds_base) {
  __builtin_amdgcn_global_load_lds(
      (const __attribute__((address_space(1))) void*)g,
      (__attribute__((address_space(3))) void*)lds_base, 16, 0, 0);
}

// ---------------- prep kernels ----------------

__global__ void k_cvt(const float* __restrict__ in, u16* __restrict__ out, int n4) {
  int i = blockIdx.x * 256 + threadIdx.x;
  if (i < n4) {
    float4 v = ((const float4*)in)[i];
    ushort4 o;
    o.x = f2bf(v.x); o.y = f2bf(v.y); o.z = f2bf(v.z); o.w = f2bf(v.w);
    ((ushort4*)out)[i] = o;
  }
}

// in [R][C] fp32 -> out [C][R] bf16   (block (32,8), grid (C/32, R/32))
__global__ void k_tc(const float* __restrict__ in, u16* __restrict__ out, int R, int C) {
  __shared__ float tile[32][33];
  int c0 = blockIdx.x * 32, r0 = blockIdx.y * 32;
  int tx = threadIdx.x, ty = threadIdx.y;
#pragma unroll
  for (int i = 0; i < 4; i++)
    tile[ty + i * 8][tx] = in[(r0 + ty + i * 8) * C + c0 + tx];
  __syncthreads();
#pragma unroll
  for (int i = 0; i < 4; i++)
    out[(size_t)(c0 + ty + i * 8) * R + r0 + tx] = f2bf(tile[tx][ty + i * 8]);
}

// W2T [64][5120] bf16: cols 0..4095 = W_rel rows, 4096..5119 = W_ctx rows; n>=51 zero
__global__ void k_w2(const float* __restrict__ W_rel, const float* __restrict__ W_ctx,
                     u16* __restrict__ out) {
  int idx = blockIdx.x * 256 + threadIdx.x;  // 64*5120
  int n = idx / 5120, k = idx % 5120;
  float v = 0.f;
  if (n < NRC) v = (k < 4096) ? W_rel[k * NRC + n] : W_ctx[(k - 4096) * NRC + n];
  out[idx] = f2bf(v);
}

// ---------------- edge embedding GEMM ----------------
// edge_rep[8192][1024] = edge_ctx[8192][512] @ W_post_emb[512][1024] + b  (bf16 out)
// A: ec_bf [8192][512] bf16 row-major(k);  Bt: WembT [1024 n][512 k] bf16
__global__ __launch_bounds__(256, 2) void k_gemm_edge(
    const u16* __restrict__ A, const u16* __restrict__ Bt,
    const float* __restrict__ bias, u16* __restrict__ C) {
  __shared__ u16 As[128 * 64];
  __shared__ u16 Bs[128 * 64];
  const int tid = threadIdx.x, w = tid >> 6, l = tid & 63;
  const int m0 = (blockIdx.x >> 3) * 128;
  const int n0 = (blockIdx.x & 7) * 128;
  const int wm = (w >> 1) * 64, wn = (w & 1) * 64;
  const int lq = l >> 4, lc = l & 15;

  f32x4 acc[4][4];
#pragma unroll
  for (int i = 0; i < 4; i++)
#pragma unroll
    for (int j = 0; j < 4; j++) acc[i][j] = (f32x4){0.f, 0.f, 0.f, 0.f};

  for (int kt = 0; kt < 8; ++kt) {
    __syncthreads();
#pragma unroll
    for (int i = 0; i < 4; i++) {
      int row = w * 32 + i * 8 + (l >> 3);
      gload16(A + (m0 + row) * 512 + kt * 64 + (l & 7) * 8, &As[w * 2048 + i * 512]);
    }
#pragma unroll
    for (int i = 0; i < 4; i++) {
      int row = w * 32 + i * 8 + (l >> 3);
      gload16(Bt + (n0 + row) * 512 + kt * 64 + (l & 7) * 8, &Bs[w * 2048 + i * 512]);
    }
    __syncthreads();
#pragma unroll
    for (int ks = 0; ks < 2; ++ks) {
      short8 af[4], bf[4];
#pragma unroll
      for (int f = 0; f < 4; f++)
        af[f] = *(const short8*)&As[(wm + f * 16 + lc) * 64 + ks * 32 + lq * 8];
#pragma unroll
      for (int f = 0; f < 4; f++)
        bf[f] = *(const short8*)&Bs[(wn + f * 16 + lc) * 64 + ks * 32 + lq * 8];
#pragma unroll
      for (int fm = 0; fm < 4; fm++)
#pragma unroll
        for (int fn = 0; fn < 4; fn++)
          acc[fm][fn] = __builtin_amdgcn_mfma_f32_16x16x32_bf16(af[fm], bf[fn], acc[fm][fn], 0, 0, 0);
    }
  }
#pragma unroll
  for (int fn = 0; fn < 4; fn++) {
    int col = n0 + wn + fn * 16 + lc;
    float b = bias[col];
#pragma unroll
    for (int fm = 0; fm < 4; fm++)
#pragma unroll
      for (int r = 0; r < 4; r++) {
        int row = m0 + wm + fm * 16 + lq * 4 + r;
        C[row * 1024 + col] = f2bf(acc[fm][fn][r] + b);
      }
  }
}

// ---------------- main fused kernel ----------------
// Per block: 128 relations. t=0..31: ctx_gate tile (GEMM1 K=1024, gathered A),
// *union -> Ps(bf16), GEMM2 accumulate vs W2T[:,t*128..]. t=32..39: Ps = prod tile
// (gathered), GEMM2 vs W_ctx part. Epilogue: wave-pair reduce + biases + freq.
__global__ __launch_bounds__(256, 2) void k_main(
    const u16* __restrict__ erep,      // [8192][1024] bf16
    const u16* __restrict__ WcatT,     // [4096 n][1024 k] bf16
    const u16* __restrict__ W2T,       // [64 n][5120 k] bf16
    const int* __restrict__ pair_idx,  // [65536][2]
    const int* __restrict__ obj_preds, // [8192]
    const float* __restrict__ uni,     // [65536][4096]
    const float* __restrict__ b_cat, const float* __restrict__ b_rel,
    const float* __restrict__ b_ctx, const float* __restrict__ freq,
    float* __restrict__ out) {
  __shared__ u16 As[128 * 64];
  __shared__ u16 Bs[128 * 64];
  __shared__ u16 Ps[128 * 128];
  const int tid = threadIdx.x, w = tid >> 6, l = tid & 63;
  const int r0 = blockIdx.x * 128;
  const int wm = (w >> 1) * 64, wn = (w & 1) * 64;
  const int lq = l >> 4, lc = l & 15;

  // rows this thread stages for A-tiles are fixed; hoist pair gathers
  int aobj[2][4];
#pragma unroll
  for (int i = 0; i < 4; i++) {
    int row = r0 + w * 32 + i * 8 + (l >> 3);
    aobj[0][i] = pair_idx[row * 2];
    aobj[1][i] = pair_idx[row * 2 + 1];
  }

  f32x4 acc2[4][4];
#pragma unroll
  for (int i = 0; i < 4; i++)
#pragma unroll
    for (int j = 0; j < 4; j++) acc2[i][j] = (f32x4){0.f, 0.f, 0.f, 0.f};

  for (int t = 0; t < 40; ++t) {
    if (t < 32) {
      f32x4 acc1[4][4];
#pragma unroll
      for (int i = 0; i < 4; i++)
#pragma unroll
        for (int j = 0; j < 4; j++) acc1[i][j] = (f32x4){0.f, 0.f, 0.f, 0.f};

      for (int kt = 0; kt < 16; ++kt) {
        __syncthreads();
        const int kh = kt >> 3;  // 0: head cols 0..511, 1: tail cols 512..1023
#pragma unroll
        for (int i = 0; i < 4; i++)
          gload16(erep + aobj[kh][i] * 1024 + kt * 64 + (l & 7) * 8,
                  &As[w * 2048 + i * 512]);
#pragma unroll
        for (int i = 0; i < 4; i++) {
          int row = w * 32 + i * 8 + (l >> 3);
          gload16(WcatT + (t * 128 + row) * 1024 + kt * 64 + (l & 7) * 8,
                  &Bs[w * 2048 + i * 512]);
        }
        __syncthreads();
#pragma unroll
        for (int ks = 0; ks < 2; ++ks) {
          short8 af[4], bf[4];
#pragma unroll
          for (int f = 0; f < 4; f++)
            af[f] = *(const short8*)&As[(wm + f * 16 + lc) * 64 + ks * 32 + lq * 8];
#pragma unroll
          for (int f = 0; f < 4; f++)
            bf[f] = *(const short8*)&Bs[(wn + f * 16 + lc) * 64 + ks * 32 + lq * 8];
#pragma unroll
          for (int fm = 0; fm < 4; fm++)
#pragma unroll
            for (int fn = 0; fn < 4; fn++)
              acc1[fm][fn] = __builtin_amdgcn_mfma_f32_16x16x32_bf16(af[fm], bf[fn], acc1[fm][fn], 0, 0, 0);
        }
      }
      // visual = (ctx_gate + b_cat) * union  -> Ps (bf16, [m][k] row-major)
#pragma unroll
      for (int fn = 0; fn < 4; fn++) {
        int col = wn + fn * 16 + lc;
        float bc = b_cat[t * 128 + col];
#pragma unroll
        for (int fm = 0; fm < 4; fm++)
#pragma unroll
          for (int r = 0; r < 4; r++) {
            int row = wm + fm * 16 + lq * 4 + r;
            float u = uni[(r0 + row) * 4096 + t * 128 + col];
            Ps[row * 128 + col] = f2bf((acc1[fm][fn][r] + bc) * u);
          }
      }
      __syncthreads();
    } else {
      __syncthreads();  // prior GEMM2 reads of Ps must drain before overwrite
      const int half = (t - 32) >> 2;  // 32..35 head, 36..39 tail
#pragma unroll
      for (int i = 0; i < 8; i++) {
        int row = w * 32 + i * 4 + (l >> 4);
        int obj = pair_idx[(r0 + row) * 2 + half];
        gload16(erep + obj * 1024 + (t - 32) * 128 + (l & 15) * 8,
                &Ps[w * 4096 + i * 512]);
      }
      __syncthreads();
    }
    // GEMM2 partial: rows wm..wm+63, k-slice wn..wn+63 of this tile
#pragma unroll
    for (int ks = 0; ks < 2; ++ks) {
      const int kk = t * 128 + wn + ks * 32;
      short8 bfr[4];
#pragma unroll
      for (int fn = 0; fn < 4; fn++)
        bfr[fn] = *(const short8*)&W2T[(fn * 16 + lc) * 5120 + kk + lq * 8];
#pragma unroll
      for (int fm = 0; fm < 4; fm++) {
        short8 af = *(const short8*)&Ps[(wm + fm * 16 + lc) * 128 + wn + ks * 32 + lq * 8];
#pragma unroll
        for (int fn = 0; fn < 4; fn++)
          acc2[fm][fn] = __builtin_amdgcn_mfma_f32_16x16x32_bf16(af, bfr[fn], acc2[fm][fn], 0, 0, 0);
      }
    }
  }

  // reduce K-halves across wave pairs (0+1 rows 0-63, 2+3 rows 64-127)
  __syncthreads();
  float* red = (float*)Ps;  // 32KB = 8192 floats, exactly 2 waves * 64 regs * 64 lanes
  if (w & 1) {
#pragma unroll
    for (int fm = 0; fm < 4; fm++)
#pragma unroll
      for (int fn = 0; fn < 4; fn++)
#pragma unroll
        for (int r = 0; r < 4; r++)
          red[(w >> 1) * 4096 + ((fm * 4 + fn) * 4 + r) * 64 + l] = acc2[fm][fn][r];
  }
  __syncthreads();
  if (!(w & 1)) {
    const float* src = red + (w >> 1) * 4096;
#pragma unroll
    for (int fm = 0; fm < 4; fm++) {
#pragma unroll
      for (int r = 0; r < 4; r++) {
        int row = r0 + wm + fm * 16 + lq * 4 + r;
        int2 pr = ((const int2*)pair_idx)[row];
        int fbase = (obj_preds[pr.x] * NOC + obj_preds[pr.y]) * NRC;
#pragma unroll
        for (int fn = 0; fn < 4; fn++) {
          int col = fn * 16 + lc;
          if (col < NRC) {
            float v = acc2[fm][fn][r] + src[((fm * 4 + fn) * 4 + r) * 64 + l] +
                      b_rel[col] + b_ctx[col] + freq[fbase + col];
            out[row * NRC + col] = v;
          }
        }
      }
    }
  }
}

// ---------------- launch ----------------

extern "C" void kernel_launch(void* const* d_in, const int* in_sizes, int n_in,
                              void* d_out, int out_size, void* d_ws, size_t ws_size,
                              hipStream_t stream) {
  const float* edge_ctx = (const float*)d_in[0];
  const int* obj_preds  = (const int*)d_in[1];
  const int* pair_idx   = (const int*)d_in[2];
  const float* uni      = (const float*)d_in[3];
  const float* W_emb    = (const float*)d_in[4];
  const float* b_emb    = (const float*)d_in[5];
  const float* W_cat    = (const float*)d_in[6];
  const float* b_cat    = (const float*)d_in[7];
  const float* W_rel    = (const float*)d_in[8];
  const float* b_rel    = (const float*)d_in[9];
  const float* W_ctx    = (const float*)d_in[10];
  const float* b_ctx    = (const float*)d_in[11];
  const float* freq     = (const float*)d_in[12];
  float* out = (float*)d_out;
  uint8_t* ws = (uint8_t*)d_ws;

  u16* ec_bf = (u16*)(ws);                       // 8192*512*2   = 8388608
  u16* WembT = (u16*)(ws + 8388608);             // 1024*512*2   = 1048576
  u16* erep  = (u16*)(ws + 9437184);             // 8192*1024*2  = 16777216
  u16* WcatT = (u16*)(ws + 26214400);            // 4096*1024*2  = 8388608
  u16* W2T   = (u16*)(ws + 34603008);            // 64*5120*2    = 655360

  k_cvt<<<4096, 256, 0, stream>>>(edge_ctx, ec_bf, 8192 * 512 / 4);
  k_tc<<<dim3(1024 / 32, 512 / 32), dim3(32, 8), 0, stream>>>(W_emb, WembT, 512, 1024);
  k_tc<<<dim3(4096 / 32, 1024 / 32), dim3(32, 8), 0, stream>>>(W_cat, WcatT, 1024, 4096);
  k_w2<<<64 * 5120 / 256, 256, 0, stream>>>(W_rel, W_ctx, W2T);
  k_gemm_edge<<<512, 256, 0, stream>>>(ec_bf, WembT, b_emb, erep);
  k_main<<<512, 256, 0, stream>>>(erep, WcatT, W2T, pair_idx, obj_preds, uni,
                                  b_cat, b_rel, b_ctx, freq, out);
}